// Round 1
// baseline (1720.838 us; speedup 1.0000x reference)
//
#include <hip/hip_runtime.h>

#define T_ 4
#define B_ 64
#define L_ 200
#define H_ 256
#define NH_ 2
#define DH_ 128

#if defined(__has_builtin)
# if __has_builtin(__builtin_amdgcn_sdot4)
#  define HAVE_SDOT4 1
# endif
#endif

__device__ __forceinline__ int dot4u(unsigned a, unsigned b, int c) {
#ifdef HAVE_SDOT4
  return __builtin_amdgcn_sdot4((int)a, (int)b, c, false);
#else
  return c + (int)((a & 255u) * (b & 255u) + ((a >> 8) & 255u) * ((b >> 8) & 255u)
                 + ((a >> 16) & 255u) * ((b >> 16) & 255u) + (a >> 24) * (b >> 24));
#endif
}

// wT[mat][k][j] = w_mat[j][k]   (4 matrices: qw,kw,vw,pw)
__global__ void transpose_w(const float* __restrict__ qw, const float* __restrict__ kw,
                            const float* __restrict__ vw, const float* __restrict__ pw,
                            float* __restrict__ wT) {
  int idx = blockIdx.x * 256 + threadIdx.x;   // 0..262143
  int mat = idx >> 16;
  int k = (idx >> 8) & 255;
  int j = idx & 255;
  const float* src = (mat == 0) ? qw : (mat == 1) ? kw : (mat == 2) ? vw : pw;
  wT[idx] = src[(j << 8) + k];
}

// Fused Linear(no bias) + LayerNorm + LIF(v_th=1) for one q/k/v branch.
// Block: 8 (b,l) pairs x 4 timesteps = 32 rows. f64 accumulation throughout.
// out: spikes u8 in [T][B][NH][L][DH]
__global__ __launch_bounds__(256)
void branch_kernel(const float* __restrict__ x, const float* __restrict__ wT,
                   const float* __restrict__ lnw, const float* __restrict__ lnb,
                   unsigned char* __restrict__ spk) {
  __shared__ double sh[32 * 256];   // 64 KB: x rows, then reused for y rows
  const int tid = threadIdx.x;
  const int p0 = blockIdx.x * 8;

  // stage x rows (row r = pair*4 + t) as f64
  for (int i = tid; i < 32 * 64; i += 256) {
    int r = i >> 6, c4 = i & 63;
    int p = r >> 2, t = r & 3;
    int pi = p0 + p;
    int b = pi / L_, l = pi % L_;
    size_t n = ((size_t)t * B_ + b) * L_ + l;
    float4 xv = ((const float4*)(x + n * H_))[c4];
    double* dst = &sh[r * 256 + c4 * 4];
    dst[0] = xv.x; dst[1] = xv.y; dst[2] = xv.z; dst[3] = xv.w;
  }
  __syncthreads();

  // GEMM: thread j owns output column j for all 32 rows, k ascending (matches np sum order)
  const int j = tid;
  double acc[32];
#pragma unroll
  for (int r = 0; r < 32; r++) acc[r] = 0.0;
  for (int k = 0; k < 256; k += 2) {
    double w0 = (double)wT[k * 256 + j];
    double w1 = (double)wT[(k + 1) * 256 + j];
#pragma unroll
    for (int r = 0; r < 32; r++) {
      double2 xv = *(const double2*)&sh[r * 256 + k];
      acc[r] += xv.x * w0;
      acc[r] += xv.y * w1;
    }
  }
  __syncthreads();
#pragma unroll
  for (int r = 0; r < 32; r++) sh[r * 256 + j] = acc[r];
  __syncthreads();

  // LayerNorm per row (two-pass, f64); wave w handles rows w*8..w*8+7
  const int wid = tid >> 6, lane = tid & 63;
  for (int ri = 0; ri < 8; ri++) {
    int r = wid * 8 + ri;
    double s = 0.0;
#pragma unroll
    for (int c = lane; c < 256; c += 64) s += sh[r * 256 + c];
#pragma unroll
    for (int o = 32; o > 0; o >>= 1) s += __shfl_xor(s, o, 64);
    double m = s * (1.0 / 256.0);
    double vs = 0.0;
#pragma unroll
    for (int c = lane; c < 256; c += 64) { double d = sh[r * 256 + c] - m; vs += d * d; }
#pragma unroll
    for (int o = 32; o > 0; o >>= 1) vs += __shfl_xor(vs, o, 64);
    double rstd = 1.0 / sqrt(vs * (1.0 / 256.0) + 1e-5);
#pragma unroll
    for (int c = lane; c < 256; c += 64)
      sh[r * 256 + c] = (sh[r * 256 + c] - m) * rstd * (double)lnw[c] + (double)lnb[c];
  }
  __syncthreads();

  // LIF over t (v=(v+y)/2; fire v>=1; hard reset) + store spikes in attention layout
  const int head = j >> 7, d = j & 127;
  for (int p = 0; p < 8; p++) {
    int pi = p0 + p;
    int b = pi / L_, l = pi % L_;
    double v = 0.0;
#pragma unroll
    for (int t = 0; t < T_; t++) {
      v = (v + sh[(p * 4 + t) * 256 + j]) * 0.5;
      bool f = (v >= 1.0);
      spk[((((size_t)t * B_ + b) * NH_ + head) * L_ + l) * DH_ + d] = f ? (unsigned char)1 : (unsigned char)0;
      if (f) v = 0.0;
    }
  }
}

// Attention (exact integer) + attn-LIF(v_th=0.5).
// Block: one (b, head, l-tile of 40); loops t=0..3 keeping membranes in registers.
__global__ __launch_bounds__(320)
void attn_kernel(const unsigned char* __restrict__ Qs, const unsigned char* __restrict__ Ks,
                 const unsigned char* __restrict__ Vs, unsigned char* __restrict__ S2) {
  __shared__ unsigned char qs[40 * 144];    // padded stride 144 kills 8-way bank conflicts
  __shared__ unsigned char ks[200 * 144];
  __shared__ unsigned short ss[40 * 200];
  const int tid = threadIdx.x;
  const int bid = blockIdx.x;
  const int lt = bid % 5;
  const int head = (bid / 5) & 1;
  const int b = bid / 10;
  const int l0 = lt * 40;
  const int lq = tid >> 3;        // 0..39
  const int mo = tid & 7;         // 0..7
  const int d0 = (tid & 7) * 16;  // 0..112

  float vmem[16];
#pragma unroll
  for (int i = 0; i < 16; i++) vmem[i] = 0.0f;

  for (int t = 0; t < T_; t++) {
    size_t base = (((size_t)t * B_ + b) * NH_ + head) * (size_t)(L_ * DH_);
    const unsigned char* Qb = Qs + base;
    const unsigned char* Kb = Ks + base;
    const unsigned char* Vb = Vs + base;
    {
      int r = tid >> 3, c = tid & 7;
      *(int4*)&qs[r * 144 + c * 16] = *(const int4*)&Qb[(size_t)(l0 + r) * DH_ + c * 16];
    }
    for (int i = tid; i < 1600; i += 320) {
      int r = i >> 3, c = i & 7;
      *(int4*)&ks[r * 144 + c * 16] = *(const int4*)&Kb[(size_t)r * DH_ + c * 16];
    }
    __syncthreads();

    // phase 1: S[lq][m] = q.k (byte dot over 128), m = mo + 8*i
    for (int i = 0; i < 25; i++) {
      int m = mo + 8 * i;
      const unsigned* qp = (const unsigned*)&qs[lq * 144];
      const unsigned* kp = (const unsigned*)&ks[m * 144];
      int dot = 0;
#pragma unroll
      for (int w = 0; w < 32; w++) dot = dot4u(qp[w], kp[w], dot);
      ss[lq * 200 + m] = (unsigned short)dot;
    }
    __syncthreads();

    // phase 2: y[lq][d0..d0+15] = sum_m S[lq][m] * V[m][d]
    int acc[16];
#pragma unroll
    for (int i = 0; i < 16; i++) acc[i] = 0;
    for (int m = 0; m < 200; m++) {
      int s = (int)ss[lq * 200 + m];
      uint4 vv = *(const uint4*)&Vb[(size_t)m * DH_ + d0];
      unsigned uw[4] = {vv.x, vv.y, vv.z, vv.w};
#pragma unroll
      for (int w = 0; w < 4; w++) {
        unsigned u = uw[w];
        acc[w * 4 + 0] += s * (int)(u & 255u);
        acc[w * 4 + 1] += s * (int)((u >> 8) & 255u);
        acc[w * 4 + 2] += s * (int)((u >> 16) & 255u);
        acc[w * 4 + 3] += s * (int)(u >> 24);
      }
    }

    // attn-LIF (exact dyadic arithmetic in f32; v_th = 0.5)
    unsigned char spb[16];
#pragma unroll
    for (int i = 0; i < 16; i++) {
      float y = (float)acc[i] * 0.125f;
      vmem[i] = (vmem[i] + y) * 0.5f;
      bool f = (vmem[i] >= 0.5f);
      spb[i] = f ? (unsigned char)1 : (unsigned char)0;
      if (f) vmem[i] = 0.0f;
    }
    size_t off = (((size_t)t * B_ + b) * L_ + (l0 + lq)) * H_ + head * DH_ + d0;
    *(int4*)&S2[off] = *(const int4*)spb;
    __syncthreads();
  }
}

// Fused proj Linear(+bias) + LayerNorm + LIF(v_th=1) -> {0,1} floats to d_out
__global__ __launch_bounds__(256)
void proj_kernel(const unsigned char* __restrict__ s2, const float* __restrict__ pwT,
                 const float* __restrict__ pb, const float* __restrict__ lnw,
                 const float* __restrict__ lnb, float* __restrict__ out) {
  __shared__ double sh[32 * 256];
  const int tid = threadIdx.x;
  const int p0 = blockIdx.x * 8;

  for (int i = tid; i < 32 * 64; i += 256) {
    int r = i >> 6, c4 = i & 63;
    int p = r >> 2, t = r & 3;
    int pi = p0 + p;
    int b = pi / L_, l = pi % L_;
    size_t n = ((size_t)t * B_ + b) * L_ + l;
    unsigned wrd = ((const unsigned*)(s2 + n * H_))[c4];
    double* dst = &sh[r * 256 + c4 * 4];
    dst[0] = (double)(wrd & 255u);
    dst[1] = (double)((wrd >> 8) & 255u);
    dst[2] = (double)((wrd >> 16) & 255u);
    dst[3] = (double)(wrd >> 24);
  }
  __syncthreads();

  const int j = tid;
  double acc[32];
  const double bj = (double)pb[j];
#pragma unroll
  for (int r = 0; r < 32; r++) acc[r] = bj;
  for (int k = 0; k < 256; k += 2) {
    double w0 = (double)pwT[k * 256 + j];
    double w1 = (double)pwT[(k + 1) * 256 + j];
#pragma unroll
    for (int r = 0; r < 32; r++) {
      double2 xv = *(const double2*)&sh[r * 256 + k];
      acc[r] += xv.x * w0;
      acc[r] += xv.y * w1;
    }
  }
  __syncthreads();
#pragma unroll
  for (int r = 0; r < 32; r++) sh[r * 256 + j] = acc[r];
  __syncthreads();

  const int wid = tid >> 6, lane = tid & 63;
  for (int ri = 0; ri < 8; ri++) {
    int r = wid * 8 + ri;
    double s = 0.0;
#pragma unroll
    for (int c = lane; c < 256; c += 64) s += sh[r * 256 + c];
#pragma unroll
    for (int o = 32; o > 0; o >>= 1) s += __shfl_xor(s, o, 64);
    double m = s * (1.0 / 256.0);
    double vs = 0.0;
#pragma unroll
    for (int c = lane; c < 256; c += 64) { double d = sh[r * 256 + c] - m; vs += d * d; }
#pragma unroll
    for (int o = 32; o > 0; o >>= 1) vs += __shfl_xor(vs, o, 64);
    double rstd = 1.0 / sqrt(vs * (1.0 / 256.0) + 1e-5);
#pragma unroll
    for (int c = lane; c < 256; c += 64)
      sh[r * 256 + c] = (sh[r * 256 + c] - m) * rstd * (double)lnw[c] + (double)lnb[c];
  }
  __syncthreads();

  for (int p = 0; p < 8; p++) {
    int pi = p0 + p;
    int b = pi / L_, l = pi % L_;
    double v = 0.0;
#pragma unroll
    for (int t = 0; t < T_; t++) {
      v = (v + sh[(p * 4 + t) * 256 + j]) * 0.5;
      bool f = (v >= 1.0);
      size_t n = ((size_t)t * B_ + b) * L_ + l;
      out[n * H_ + j] = f ? 1.0f : 0.0f;
      if (f) v = 0.0;
    }
  }
}

extern "C" void kernel_launch(void* const* d_in, const int* in_sizes, int n_in,
                              void* d_out, int out_size, void* d_ws, size_t ws_size,
                              hipStream_t stream) {
  (void)in_sizes; (void)n_in; (void)out_size; (void)ws_size;
  const float* x    = (const float*)d_in[0];
  const float* qw   = (const float*)d_in[1];
  const float* qlnw = (const float*)d_in[2];
  const float* qlnb = (const float*)d_in[3];
  const float* kw   = (const float*)d_in[4];
  const float* klnw = (const float*)d_in[5];
  const float* klnb = (const float*)d_in[6];
  const float* vw   = (const float*)d_in[7];
  const float* vlnw = (const float*)d_in[8];
  const float* vlnb = (const float*)d_in[9];
  const float* pw   = (const float*)d_in[10];
  const float* pb   = (const float*)d_in[11];
  const float* plnw = (const float*)d_in[12];
  const float* plnb = (const float*)d_in[13];

  char* ws = (char*)d_ws;
  float* wT = (float*)ws;                                  // 4 * 64K floats = 1 MB
  const size_t SPK = (size_t)T_ * B_ * NH_ * L_ * DH_;     // 13,107,200 bytes each
  unsigned char* Qsp = (unsigned char*)(ws + (1 << 20));
  unsigned char* Ksp = Qsp + SPK;
  unsigned char* Vsp = Ksp + SPK;
  unsigned char* S2  = Vsp + SPK;                          // total ~53.4 MB of ws

  hipLaunchKernelGGL(transpose_w, dim3(1024), dim3(256), 0, stream, qw, kw, vw, pw, wT);
  hipLaunchKernelGGL(branch_kernel, dim3(1600), dim3(256), 0, stream, x, wT,          qlnw, qlnb, Qsp);
  hipLaunchKernelGGL(branch_kernel, dim3(1600), dim3(256), 0, stream, x, wT + 65536,  klnw, klnb, Ksp);
  hipLaunchKernelGGL(branch_kernel, dim3(1600), dim3(256), 0, stream, x, wT + 131072, vlnw, vlnb, Vsp);
  hipLaunchKernelGGL(attn_kernel, dim3(640), dim3(320), 0, stream, Qsp, Ksp, Vsp, S2);
  hipLaunchKernelGGL(proj_kernel, dim3(1600), dim3(256), 0, stream, S2, wT + 196608, pb, plnw, plnb, (float*)d_out);
}

// Round 2
// 1211.756 us; speedup vs baseline: 1.4201x; 1.4201x over previous
//
#include <hip/hip_runtime.h>

#define T_ 4
#define B_ 64
#define L_ 200
#define H_ 256
#define NH_ 2
#define DH_ 128

typedef short short8_t __attribute__((ext_vector_type(8)));
typedef float f32x4 __attribute__((ext_vector_type(4)));

// 8 spike bytes ({0,1}) -> 8 bf16 ({0,1.0}) packed as short8.
// per 4 bytes: 2 v_perm (spread bytes to 16-bit lanes) + 2 mul by 0x3F80.
__device__ __forceinline__ short8_t unpack_bf16(uint2 v) {
  union { short8_t s; unsigned u[4]; } r;
  r.u[0] = __builtin_amdgcn_perm(0u, v.x, 0x0C010C00u) * 0x3F80u;
  r.u[1] = __builtin_amdgcn_perm(0u, v.x, 0x0C030C02u) * 0x3F80u;
  r.u[2] = __builtin_amdgcn_perm(0u, v.y, 0x0C010C00u) * 0x3F80u;
  r.u[3] = __builtin_amdgcn_perm(0u, v.y, 0x0C030C02u) * 0x3F80u;
  return r.s;
}

// wT[mat][k][j] = w_mat[j][k]   (4 matrices: qw,kw,vw,pw)
__global__ void transpose_w(const float* __restrict__ qw, const float* __restrict__ kw,
                            const float* __restrict__ vw, const float* __restrict__ pw,
                            float* __restrict__ wT) {
  int idx = blockIdx.x * 256 + threadIdx.x;   // 0..262143
  int mat = idx >> 16;
  int k = (idx >> 8) & 255;
  int j = idx & 255;
  const float* src = (mat == 0) ? qw : (mat == 1) ? kw : (mat == 2) ? vw : pw;
  wT[idx] = src[(j << 8) + k];
}

// Fused Linear(no bias) + LayerNorm + LIF(v_th=1) for one q/k/v branch.
// Block: 8 (b,l) pairs x 4 timesteps = 32 rows. f64 accumulation throughout.
// out: spikes u8 in [T][B][NH][L][DH]
__global__ __launch_bounds__(256)
void branch_kernel(const float* __restrict__ x, const float* __restrict__ wT,
                   const float* __restrict__ lnw, const float* __restrict__ lnb,
                   unsigned char* __restrict__ spk) {
  __shared__ double sh[32 * 256];   // 64 KB: x rows, then reused for y rows
  const int tid = threadIdx.x;
  const int p0 = blockIdx.x * 8;

  // stage x rows (row r = pair*4 + t) as f64
  for (int i = tid; i < 32 * 64; i += 256) {
    int r = i >> 6, c4 = i & 63;
    int p = r >> 2, t = r & 3;
    int pi = p0 + p;
    int b = pi / L_, l = pi % L_;
    size_t n = ((size_t)t * B_ + b) * L_ + l;
    float4 xv = ((const float4*)(x + n * H_))[c4];
    double* dst = &sh[r * 256 + c4 * 4];
    dst[0] = xv.x; dst[1] = xv.y; dst[2] = xv.z; dst[3] = xv.w;
  }
  __syncthreads();

  // GEMM: thread j owns output column j for all 32 rows, k ascending
  const int j = tid;
  double acc[32];
#pragma unroll
  for (int r = 0; r < 32; r++) acc[r] = 0.0;
  for (int k = 0; k < 256; k += 2) {
    double w0 = (double)wT[k * 256 + j];
    double w1 = (double)wT[(k + 1) * 256 + j];
#pragma unroll
    for (int r = 0; r < 32; r++) {
      double2 xv = *(const double2*)&sh[r * 256 + k];
      acc[r] += xv.x * w0;
      acc[r] += xv.y * w1;
    }
  }
  __syncthreads();
#pragma unroll
  for (int r = 0; r < 32; r++) sh[r * 256 + j] = acc[r];
  __syncthreads();

  // LayerNorm per row (two-pass, f64); wave w handles rows w*8..w*8+7
  const int wid = tid >> 6, lane = tid & 63;
  for (int ri = 0; ri < 8; ri++) {
    int r = wid * 8 + ri;
    double s = 0.0;
#pragma unroll
    for (int c = lane; c < 256; c += 64) s += sh[r * 256 + c];
#pragma unroll
    for (int o = 32; o > 0; o >>= 1) s += __shfl_xor(s, o, 64);
    double m = s * (1.0 / 256.0);
    double vs = 0.0;
#pragma unroll
    for (int c = lane; c < 256; c += 64) { double d = sh[r * 256 + c] - m; vs += d * d; }
#pragma unroll
    for (int o = 32; o > 0; o >>= 1) vs += __shfl_xor(vs, o, 64);
    double rstd = 1.0 / sqrt(vs * (1.0 / 256.0) + 1e-5);
#pragma unroll
    for (int c = lane; c < 256; c += 64)
      sh[r * 256 + c] = (sh[r * 256 + c] - m) * rstd * (double)lnw[c] + (double)lnb[c];
  }
  __syncthreads();

  // LIF over t (v=(v+y)/2; fire v>=1; hard reset) + store spikes
  const int head = j >> 7, d = j & 127;
  for (int p = 0; p < 8; p++) {
    int pi = p0 + p;
    int b = pi / L_, l = pi % L_;
    double v = 0.0;
#pragma unroll
    for (int t = 0; t < T_; t++) {
      v = (v + sh[(p * 4 + t) * 256 + j]) * 0.5;
      bool f = (v >= 1.0);
      spk[((((size_t)t * B_ + b) * NH_ + head) * L_ + l) * DH_ + d] = f ? (unsigned char)1 : (unsigned char)0;
      if (f) v = 0.0;
    }
  }
}

// V spikes [slab][m<200][d] u8 -> Vt [slab][d][m<224] u8, zero-padded m>=200.
// Column reads are L1-resident (25.6KB slab); writes coalesced 64B.
__global__ __launch_bounds__(256)
void vt_prep(const unsigned char* __restrict__ Vs, unsigned char* __restrict__ Vt) {
  const int slab = blockIdx.x;            // 512
  const int w = threadIdx.x >> 6, lane = threadIdx.x & 63;
  const unsigned char* src = Vs + (size_t)slab * (L_ * DH_);
  unsigned char* dst = Vt + (size_t)slab * (DH_ * 224);
  for (int d = w; d < DH_; d += 4) {
    for (int mb = 0; mb < 4; mb++) {
      int m = mb * 64 + lane;
      unsigned char v = 0;
      if (m < L_) v = src[(size_t)m * DH_ + d];
      if (m < 224) dst[(size_t)d * 224 + m] = v;
    }
  }
}

// MFMA attention + attn-LIF(v_th=0.5). Exact: spikes are {0,1.0} bf16,
// QK dots <=128 (exact bf16 via >>16), SV sums <=25600 << 2^24 in f32.
// Block: (b, head, 32-row l-tile), 4 waves. t-loop keeps membranes in regs.
// Wave w: QK n-tiles {w, w+4, w+8, w+12}, SV d-tiles {w, w+4}.
__global__ __launch_bounds__(256)
void attn_mfma(const unsigned char* __restrict__ Qs, const unsigned char* __restrict__ Ks,
               const unsigned char* __restrict__ Vt, unsigned char* __restrict__ S2) {
  __shared__ unsigned short sS[32 * 232];   // S in bf16, stride 232 (116w: 2-way banks, 16B-aligned rows)
  const int tid = threadIdx.x;
  const int w = tid >> 6, lane = tid & 63;
  const int quad = lane >> 4, ln = lane & 15;
  const int bid = blockIdx.x;
  const int lt = bid % 7;
  const int head = (bid / 7) & 1;
  const int b = bid / 14;
  const int l0 = lt * 32;

  // zero S once (pad cols 208..223 must stay 0; QK writes only cols<208)
  for (int i = tid; i < 32 * 232; i += 256) sS[i] = 0;

  float vmem[2][2][4];
#pragma unroll
  for (int di = 0; di < 2; di++)
#pragma unroll
    for (int ls = 0; ls < 2; ls++)
#pragma unroll
      for (int r = 0; r < 4; r++) vmem[di][ls][r] = 0.f;

  __syncthreads();

  for (int t = 0; t < T_; t++) {
    const int slab = (t * B_ + b) * NH_ + head;
    const unsigned char* qb = Qs + (size_t)slab * (L_ * DH_) + (size_t)l0 * DH_;
    const unsigned char* kb = Ks + (size_t)slab * (L_ * DH_);

    // ---- QK^T: A = Q rows (A[m=ln][k=quad*8+j]), B = K rows (B[k][n=ln]) ----
    short8_t af[2][4];
#pragma unroll
    for (int ls = 0; ls < 2; ls++)
#pragma unroll
      for (int ks = 0; ks < 4; ks++)
        af[ls][ks] = unpack_bf16(*(const uint2*)(qb + (size_t)(ls * 16 + ln) * DH_ + ks * 32 + quad * 8));

#pragma unroll
    for (int i = 0; i < 4; i++) {
      int nt = w + 4 * i;
      if (nt < 13) {
        short8_t bf[4];
#pragma unroll
        for (int ks = 0; ks < 4; ks++)
          bf[ks] = unpack_bf16(*(const uint2*)(kb + (size_t)(nt * 16 + ln) * DH_ + ks * 32 + quad * 8));
#pragma unroll
        for (int ls = 0; ls < 2; ls++) {
          f32x4 acc = {0.f, 0.f, 0.f, 0.f};
#pragma unroll
          for (int ks = 0; ks < 4; ks++)
            acc = __builtin_amdgcn_mfma_f32_16x16x32_bf16(af[ls][ks], bf[ks], acc, 0, 0, 0);
          // D row = quad*4+reg (l-local), col = ln (key). Store bf16 (exact, <=128).
#pragma unroll
          for (int r = 0; r < 4; r++)
            sS[(ls * 16 + quad * 4 + r) * 232 + nt * 16 + ln] =
                (unsigned short)(__float_as_uint(acc[r]) >> 16);
        }
      }
    }
    __syncthreads();

    // ---- S·V: A = S from LDS (A-layout), B = Vt rows (B[k=m][n=d]) ----
    const unsigned char* vb = Vt + (size_t)slab * (DH_ * 224);
    f32x4 a2[2][2];
#pragma unroll
    for (int di = 0; di < 2; di++)
#pragma unroll
      for (int ls = 0; ls < 2; ls++) { f32x4 z = {0.f, 0.f, 0.f, 0.f}; a2[di][ls] = z; }

#pragma unroll
    for (int ks = 0; ks < 7; ks++) {
      short8_t s0 = *(const short8_t*)&sS[(0 * 16 + ln) * 232 + ks * 32 + quad * 8];
      short8_t s1 = *(const short8_t*)&sS[(1 * 16 + ln) * 232 + ks * 32 + quad * 8];
#pragma unroll
      for (int di = 0; di < 2; di++) {
        int dt = w + 4 * di;
        short8_t bv = unpack_bf16(*(const uint2*)(vb + (size_t)(dt * 16 + ln) * 224 + ks * 32 + quad * 8));
        a2[di][0] = __builtin_amdgcn_mfma_f32_16x16x32_bf16(s0, bv, a2[di][0], 0, 0, 0);
        a2[di][1] = __builtin_amdgcn_mfma_f32_16x16x32_bf16(s1, bv, a2[di][1], 0, 0, 0);
      }
    }

    // ---- attn-LIF (exact dyadic f32) + byte store ----
#pragma unroll
    for (int di = 0; di < 2; di++)
#pragma unroll
      for (int ls = 0; ls < 2; ls++)
#pragma unroll
        for (int r = 0; r < 4; r++) {
          float y = a2[di][ls][r] * 0.125f;
          float v = (vmem[di][ls][r] + y) * 0.5f;
          bool f = (v >= 0.5f);
          int l = l0 + ls * 16 + quad * 4 + r;
          if (l < L_)
            S2[(((size_t)t * B_ + b) * L_ + l) * H_ + head * DH_ + (w + 4 * di) * 16 + ln] =
                f ? (unsigned char)1 : (unsigned char)0;
          vmem[di][ls][r] = f ? 0.f : v;
        }
    __syncthreads();   // protect sS before next t's QK writes
  }
}

// Fused proj Linear(+bias) + LayerNorm + LIF(v_th=1) -> {0,1} floats to d_out
__global__ __launch_bounds__(256)
void proj_kernel(const unsigned char* __restrict__ s2, const float* __restrict__ pwT,
                 const float* __restrict__ pb, const float* __restrict__ lnw,
                 const float* __restrict__ lnb, float* __restrict__ out) {
  __shared__ double sh[32 * 256];
  const int tid = threadIdx.x;
  const int p0 = blockIdx.x * 8;

  for (int i = tid; i < 32 * 64; i += 256) {
    int r = i >> 6, c4 = i & 63;
    int p = r >> 2, t = r & 3;
    int pi = p0 + p;
    int b = pi / L_, l = pi % L_;
    size_t n = ((size_t)t * B_ + b) * L_ + l;
    unsigned wrd = ((const unsigned*)(s2 + n * H_))[c4];
    double* dst = &sh[r * 256 + c4 * 4];
    dst[0] = (double)(wrd & 255u);
    dst[1] = (double)((wrd >> 8) & 255u);
    dst[2] = (double)((wrd >> 16) & 255u);
    dst[3] = (double)(wrd >> 24);
  }
  __syncthreads();

  const int j = tid;
  double acc[32];
  const double bj = (double)pb[j];
#pragma unroll
  for (int r = 0; r < 32; r++) acc[r] = bj;
  for (int k = 0; k < 256; k += 2) {
    double w0 = (double)pwT[k * 256 + j];
    double w1 = (double)pwT[(k + 1) * 256 + j];
#pragma unroll
    for (int r = 0; r < 32; r++) {
      double2 xv = *(const double2*)&sh[r * 256 + k];
      acc[r] += xv.x * w0;
      acc[r] += xv.y * w1;
    }
  }
  __syncthreads();
#pragma unroll
  for (int r = 0; r < 32; r++) sh[r * 256 + j] = acc[r];
  __syncthreads();

  const int wid = tid >> 6, lane = tid & 63;
  for (int ri = 0; ri < 8; ri++) {
    int r = wid * 8 + ri;
    double s = 0.0;
#pragma unroll
    for (int c = lane; c < 256; c += 64) s += sh[r * 256 + c];
#pragma unroll
    for (int o = 32; o > 0; o >>= 1) s += __shfl_xor(s, o, 64);
    double m = s * (1.0 / 256.0);
    double vs = 0.0;
#pragma unroll
    for (int c = lane; c < 256; c += 64) { double d = sh[r * 256 + c] - m; vs += d * d; }
#pragma unroll
    for (int o = 32; o > 0; o >>= 1) vs += __shfl_xor(vs, o, 64);
    double rstd = 1.0 / sqrt(vs * (1.0 / 256.0) + 1e-5);
#pragma unroll
    for (int c = lane; c < 256; c += 64)
      sh[r * 256 + c] = (sh[r * 256 + c] - m) * rstd * (double)lnw[c] + (double)lnb[c];
  }
  __syncthreads();

  for (int p = 0; p < 8; p++) {
    int pi = p0 + p;
    int b = pi / L_, l = pi % L_;
    double v = 0.0;
#pragma unroll
    for (int t = 0; t < T_; t++) {
      v = (v + sh[(p * 4 + t) * 256 + j]) * 0.5;
      bool f = (v >= 1.0);
      size_t n = ((size_t)t * B_ + b) * L_ + l;
      out[n * H_ + j] = f ? 1.0f : 0.0f;
      if (f) v = 0.0;
    }
  }
}

extern "C" void kernel_launch(void* const* d_in, const int* in_sizes, int n_in,
                              void* d_out, int out_size, void* d_ws, size_t ws_size,
                              hipStream_t stream) {
  (void)in_sizes; (void)n_in; (void)out_size; (void)ws_size;
  const float* x    = (const float*)d_in[0];
  const float* qw   = (const float*)d_in[1];
  const float* qlnw = (const float*)d_in[2];
  const float* qlnb = (const float*)d_in[3];
  const float* kw   = (const float*)d_in[4];
  const float* klnw = (const float*)d_in[5];
  const float* klnb = (const float*)d_in[6];
  const float* vw   = (const float*)d_in[7];
  const float* vlnw = (const float*)d_in[8];
  const float* vlnb = (const float*)d_in[9];
  const float* pw   = (const float*)d_in[10];
  const float* pb   = (const float*)d_in[11];
  const float* plnw = (const float*)d_in[12];
  const float* plnb = (const float*)d_in[13];

  char* ws = (char*)d_ws;
  const size_t SPK = (size_t)T_ * B_ * NH_ * L_ * DH_;     // 13,107,200 bytes
  const size_t VTS = (size_t)T_ * B_ * NH_ * DH_ * 224;    // 14,680,064 bytes
  float* wT = (float*)ws;                                  // 1 MB
  unsigned char* Qsp = (unsigned char*)(ws + (1 << 20));
  unsigned char* Ksp = Qsp + SPK;
  unsigned char* Vsp = Ksp + SPK;
  unsigned char* S2  = Vsp;                                // alias: Vsp dead after vt_prep
  unsigned char* Vt  = Vsp + SPK;                          // total ~52.5 MB

  hipLaunchKernelGGL(transpose_w, dim3(1024), dim3(256), 0, stream, qw, kw, vw, pw, wT);
  hipLaunchKernelGGL(branch_kernel, dim3(1600), dim3(256), 0, stream, x, wT,          qlnw, qlnb, Qsp);
  hipLaunchKernelGGL(branch_kernel, dim3(1600), dim3(256), 0, stream, x, wT + 65536,  klnw, klnb, Ksp);
  hipLaunchKernelGGL(branch_kernel, dim3(1600), dim3(256), 0, stream, x, wT + 131072, vlnw, vlnb, Vsp);
  hipLaunchKernelGGL(vt_prep, dim3(512), dim3(256), 0, stream, Vsp, Vt);
  hipLaunchKernelGGL(attn_mfma, dim3(896), dim3(256), 0, stream, Qsp, Ksp, Vt, S2);
  hipLaunchKernelGGL(proj_kernel, dim3(1600), dim3(256), 0, stream, S2, wT + 196608, pb, plnw, plnb, (float*)d_out);
}

// Round 3
// 1083.699 us; speedup vs baseline: 1.5879x; 1.1182x over previous
//
#include <hip/hip_runtime.h>

#define T_ 4
#define B_ 64
#define L_ 200
#define H_ 256
#define NH_ 2
#define DH_ 128

typedef short short8_t __attribute__((ext_vector_type(8)));
typedef float f32x4 __attribute__((ext_vector_type(4)));

// 8 spike bytes ({0,1}) -> 8 bf16 ({0,1.0}) packed as short8.
__device__ __forceinline__ short8_t unpack_bf16(uint2 v) {
  union { short8_t s; unsigned u[4]; } r;
  r.u[0] = __builtin_amdgcn_perm(0u, v.x, 0x0C010C00u) * 0x3F80u;
  r.u[1] = __builtin_amdgcn_perm(0u, v.x, 0x0C030C02u) * 0x3F80u;
  r.u[2] = __builtin_amdgcn_perm(0u, v.y, 0x0C010C00u) * 0x3F80u;
  r.u[3] = __builtin_amdgcn_perm(0u, v.y, 0x0C030C02u) * 0x3F80u;
  return r.s;
}

// wT[mat][k][j] = w_mat[j][k]   (4 matrices: qw,kw,vw,pw)
__global__ void transpose_w(const float* __restrict__ qw, const float* __restrict__ kw,
                            const float* __restrict__ vw, const float* __restrict__ pw,
                            float* __restrict__ wT) {
  int idx = blockIdx.x * 256 + threadIdx.x;   // 0..262143
  int mat = idx >> 16;
  int k = (idx >> 8) & 255;
  int j = idx & 255;
  const float* src = (mat == 0) ? qw : (mat == 1) ? kw : (mat == 2) ? vw : pw;
  wT[idx] = src[(j << 8) + k];
}

// Fused Linear(no bias) + LayerNorm + LIF(v_th=1), f64 semantics identical to
// the passing R1 kernel (ascending-k sum, (acc-m)*rstd*lw+lb, v=(v+y)*0.5).
// 16 rows/block (4 (b,l) pairs x 4 t); 256 thr = 128 cols x 2 row-halves;
// thread = 2 cols x 8 rows. LDS 33KB -> 4 blocks/CU (16 waves).
__global__ __launch_bounds__(256)
void branch_kernel(const float* __restrict__ x, const float* __restrict__ wT,
                   const float* __restrict__ lnw, const float* __restrict__ lnb,
                   unsigned char* __restrict__ spk) {
  __shared__ double sh[16 * 256];   // 32 KB x-tile (f64)
  __shared__ double red[4][8];      // per-wave partials
  __shared__ double rstd_s[16];
  const int tid = threadIdx.x;
  const int c = tid & 127, rh = tid >> 7;
  const int w = tid >> 6;
  const int p0 = blockIdx.x * 4;

  // stage 16 rows of x as f64 (coalesced f32 reads)
  for (int i = tid; i < 4096; i += 256) {
    int r = i >> 8, k = i & 255;
    int p = r >> 2, t = r & 3;
    int pi = p0 + p;
    int b = pi / L_, l = pi % L_;
    sh[i] = (double)x[(((size_t)t * B_ + b) * L_ + l) * H_ + k];
  }
  __syncthreads();

  // GEMM: thread -> cols {c, c+128}, rows rh*8..rh*8+7, k ascending
  double acc[8][2];
#pragma unroll
  for (int i = 0; i < 8; i++) { acc[i][0] = 0.0; acc[i][1] = 0.0; }
#pragma unroll 4
  for (int k = 0; k < 256; k += 2) {
    double wa0 = (double)wT[k * 256 + c];
    double wa1 = (double)wT[(k + 1) * 256 + c];
    double wb0 = (double)wT[k * 256 + c + 128];
    double wb1 = (double)wT[(k + 1) * 256 + c + 128];
#pragma unroll
    for (int i = 0; i < 8; i++) {
      double2 xv = *(const double2*)&sh[(rh * 8 + i) * 256 + k];
      acc[i][0] += xv.x * wa0;
      acc[i][0] += xv.y * wa1;
      acc[i][1] += xv.x * wb0;
      acc[i][1] += xv.y * wb1;
    }
  }

  // LayerNorm stats in registers + shuffle + tiny LDS scratch
  double m_[8];
#pragma unroll
  for (int i = 0; i < 8; i++) {
    double s = acc[i][0] + acc[i][1];
#pragma unroll
    for (int o = 32; o > 0; o >>= 1) s += __shfl_xor(s, o, 64);
    if ((tid & 63) == 0) red[w][i] = s;
  }
  __syncthreads();
#pragma unroll
  for (int i = 0; i < 8; i++)
    m_[i] = (red[rh * 2][i] + red[rh * 2 + 1][i]) * (1.0 / 256.0);
  __syncthreads();
#pragma unroll
  for (int i = 0; i < 8; i++) {
    double d0 = acc[i][0] - m_[i], d1 = acc[i][1] - m_[i];
    double ss = d0 * d0 + d1 * d1;
#pragma unroll
    for (int o = 32; o > 0; o >>= 1) ss += __shfl_xor(ss, o, 64);
    if ((tid & 63) == 0) red[w][i] = ss;
  }
  __syncthreads();
  if (tid < 16) {
    int i = tid & 7, base = (tid >> 3) * 2;
    double var = (red[base][i] + red[base + 1][i]) * (1.0 / 256.0);
    rstd_s[tid] = 1.0 / sqrt(var + 1e-5);
  }
  __syncthreads();
  double rs_[8];
#pragma unroll
  for (int i = 0; i < 8; i++) rs_[i] = rstd_s[rh * 8 + i];

  const double lw0 = (double)lnw[c], lb0 = (double)lnb[c];
  const double lw1 = (double)lnw[c + 128], lb1 = (double)lnb[c + 128];

  // LIF over t from registers + spike store
#pragma unroll
  for (int cc = 0; cc < 2; cc++) {
    int col = c + cc * 128;
    int head = col >> 7, d = col & 127;
    double lw = cc ? lw1 : lw0, lb = cc ? lb1 : lb0;
#pragma unroll
    for (int pl = 0; pl < 2; pl++) {
      int pi = p0 + rh * 2 + pl;
      int b = pi / L_, l = pi % L_;
      double v = 0.0;
#pragma unroll
      for (int t = 0; t < 4; t++) {
        int i = pl * 4 + t;
        double yn = (acc[i][cc] - m_[i]) * rs_[i] * lw + lb;
        v = (v + yn) * 0.5;
        bool f = (v >= 1.0);
        spk[((((size_t)t * B_ + b) * NH_ + head) * L_ + l) * DH_ + d] = f ? (unsigned char)1 : (unsigned char)0;
        if (f) v = 0.0;
      }
    }
  }
}

// V spikes [slab][m<200][d] u8 -> Vt [slab][d][m<224] u8, zero-padded m>=200.
__global__ __launch_bounds__(256)
void vt_prep(const unsigned char* __restrict__ Vs, unsigned char* __restrict__ Vt) {
  const int slab = blockIdx.x;            // 512
  const int w = threadIdx.x >> 6, lane = threadIdx.x & 63;
  const unsigned char* src = Vs + (size_t)slab * (L_ * DH_);
  unsigned char* dst = Vt + (size_t)slab * (DH_ * 224);
  for (int d = w; d < DH_; d += 4) {
    for (int mb = 0; mb < 4; mb++) {
      int m = mb * 64 + lane;
      unsigned char v = 0;
      if (m < L_) v = src[(size_t)m * DH_ + d];
      if (m < 224) dst[(size_t)d * 224 + m] = v;
    }
  }
}

// MFMA attention + attn-LIF(v_th=0.5). Exact (spikes {0,1}, dots <=128, sums <=25600).
__global__ __launch_bounds__(256)
void attn_mfma(const unsigned char* __restrict__ Qs, const unsigned char* __restrict__ Ks,
               const unsigned char* __restrict__ Vt, unsigned char* __restrict__ S2) {
  __shared__ unsigned short sS[32 * 232];
  const int tid = threadIdx.x;
  const int w = tid >> 6, lane = tid & 63;
  const int quad = lane >> 4, ln = lane & 15;
  const int bid = blockIdx.x;
  const int lt = bid % 7;
  const int head = (bid / 7) & 1;
  const int b = bid / 14;
  const int l0 = lt * 32;

  for (int i = tid; i < 32 * 232; i += 256) sS[i] = 0;

  float vmem[2][2][4];
#pragma unroll
  for (int di = 0; di < 2; di++)
#pragma unroll
    for (int ls = 0; ls < 2; ls++)
#pragma unroll
      for (int r = 0; r < 4; r++) vmem[di][ls][r] = 0.f;

  __syncthreads();

  for (int t = 0; t < T_; t++) {
    const int slab = (t * B_ + b) * NH_ + head;
    const unsigned char* qb = Qs + (size_t)slab * (L_ * DH_) + (size_t)l0 * DH_;
    const unsigned char* kb = Ks + (size_t)slab * (L_ * DH_);

    short8_t af[2][4];
#pragma unroll
    for (int ls = 0; ls < 2; ls++)
#pragma unroll
      for (int ks = 0; ks < 4; ks++)
        af[ls][ks] = unpack_bf16(*(const uint2*)(qb + (size_t)(ls * 16 + ln) * DH_ + ks * 32 + quad * 8));

#pragma unroll
    for (int i = 0; i < 4; i++) {
      int nt = w + 4 * i;
      if (nt < 13) {
        short8_t bf[4];
#pragma unroll
        for (int ks = 0; ks < 4; ks++)
          bf[ks] = unpack_bf16(*(const uint2*)(kb + (size_t)(nt * 16 + ln) * DH_ + ks * 32 + quad * 8));
#pragma unroll
        for (int ls = 0; ls < 2; ls++) {
          f32x4 acc = {0.f, 0.f, 0.f, 0.f};
#pragma unroll
          for (int ks = 0; ks < 4; ks++)
            acc = __builtin_amdgcn_mfma_f32_16x16x32_bf16(af[ls][ks], bf[ks], acc, 0, 0, 0);
#pragma unroll
          for (int r = 0; r < 4; r++)
            sS[(ls * 16 + quad * 4 + r) * 232 + nt * 16 + ln] =
                (unsigned short)(__float_as_uint(acc[r]) >> 16);
        }
      }
    }
    __syncthreads();

    const unsigned char* vb = Vt + (size_t)slab * (DH_ * 224);
    f32x4 a2[2][2];
#pragma unroll
    for (int di = 0; di < 2; di++)
#pragma unroll
      for (int ls = 0; ls < 2; ls++) { f32x4 z = {0.f, 0.f, 0.f, 0.f}; a2[di][ls] = z; }

#pragma unroll
    for (int ks = 0; ks < 7; ks++) {
      short8_t s0 = *(const short8_t*)&sS[(0 * 16 + ln) * 232 + ks * 32 + quad * 8];
      short8_t s1 = *(const short8_t*)&sS[(1 * 16 + ln) * 232 + ks * 32 + quad * 8];
#pragma unroll
      for (int di = 0; di < 2; di++) {
        int dt = w + 4 * di;
        short8_t bv = unpack_bf16(*(const uint2*)(vb + (size_t)(dt * 16 + ln) * 224 + ks * 32 + quad * 8));
        a2[di][0] = __builtin_amdgcn_mfma_f32_16x16x32_bf16(s0, bv, a2[di][0], 0, 0, 0);
        a2[di][1] = __builtin_amdgcn_mfma_f32_16x16x32_bf16(s1, bv, a2[di][1], 0, 0, 0);
      }
    }

#pragma unroll
    for (int di = 0; di < 2; di++)
#pragma unroll
      for (int ls = 0; ls < 2; ls++)
#pragma unroll
        for (int r = 0; r < 4; r++) {
          float y = a2[di][ls][r] * 0.125f;
          float v = (vmem[di][ls][r] + y) * 0.5f;
          bool f = (v >= 0.5f);
          int l = l0 + ls * 16 + quad * 4 + r;
          if (l < L_)
            S2[(((size_t)t * B_ + b) * L_ + l) * H_ + head * DH_ + (w + 4 * di) * 16 + ln] =
                f ? (unsigned char)1 : (unsigned char)0;
          vmem[di][ls][r] = f ? 0.f : v;
        }
    __syncthreads();
  }
}

// Fused proj Linear(+bias) + LayerNorm + LIF(v_th=1) -> {0,1} floats.
// Same restructure as branch_kernel; spikes staged as f64 once.
__global__ __launch_bounds__(256)
void proj_kernel(const unsigned char* __restrict__ s2, const float* __restrict__ pwT,
                 const float* __restrict__ pb, const float* __restrict__ lnw,
                 const float* __restrict__ lnb, float* __restrict__ out) {
  __shared__ double sh[16 * 256];
  __shared__ double red[4][8];
  __shared__ double rstd_s[16];
  const int tid = threadIdx.x;
  const int c = tid & 127, rh = tid >> 7;
  const int w = tid >> 6;
  const int p0 = blockIdx.x * 4;

  for (int i = tid; i < 4096; i += 256) {
    int r = i >> 8, k = i & 255;
    int p = r >> 2, t = r & 3;
    int pi = p0 + p;
    int b = pi / L_, l = pi % L_;
    sh[i] = (double)s2[(((size_t)t * B_ + b) * L_ + l) * H_ + k];
  }
  __syncthreads();

  double acc[8][2];
  const double bj0 = (double)pb[c], bj1 = (double)pb[c + 128];
#pragma unroll
  for (int i = 0; i < 8; i++) { acc[i][0] = bj0; acc[i][1] = bj1; }
#pragma unroll 4
  for (int k = 0; k < 256; k += 2) {
    double wa0 = (double)pwT[k * 256 + c];
    double wa1 = (double)pwT[(k + 1) * 256 + c];
    double wb0 = (double)pwT[k * 256 + c + 128];
    double wb1 = (double)pwT[(k + 1) * 256 + c + 128];
#pragma unroll
    for (int i = 0; i < 8; i++) {
      double2 xv = *(const double2*)&sh[(rh * 8 + i) * 256 + k];
      acc[i][0] += xv.x * wa0;
      acc[i][0] += xv.y * wa1;
      acc[i][1] += xv.x * wb0;
      acc[i][1] += xv.y * wb1;
    }
  }

  double m_[8];
#pragma unroll
  for (int i = 0; i < 8; i++) {
    double s = acc[i][0] + acc[i][1];
#pragma unroll
    for (int o = 32; o > 0; o >>= 1) s += __shfl_xor(s, o, 64);
    if ((tid & 63) == 0) red[w][i] = s;
  }
  __syncthreads();
#pragma unroll
  for (int i = 0; i < 8; i++)
    m_[i] = (red[rh * 2][i] + red[rh * 2 + 1][i]) * (1.0 / 256.0);
  __syncthreads();
#pragma unroll
  for (int i = 0; i < 8; i++) {
    double d0 = acc[i][0] - m_[i], d1 = acc[i][1] - m_[i];
    double ss = d0 * d0 + d1 * d1;
#pragma unroll
    for (int o = 32; o > 0; o >>= 1) ss += __shfl_xor(ss, o, 64);
    if ((tid & 63) == 0) red[w][i] = ss;
  }
  __syncthreads();
  if (tid < 16) {
    int i = tid & 7, base = (tid >> 3) * 2;
    double var = (red[base][i] + red[base + 1][i]) * (1.0 / 256.0);
    rstd_s[tid] = 1.0 / sqrt(var + 1e-5);
  }
  __syncthreads();
  double rs_[8];
#pragma unroll
  for (int i = 0; i < 8; i++) rs_[i] = rstd_s[rh * 8 + i];

  const double lw0 = (double)lnw[c], lb0 = (double)lnb[c];
  const double lw1 = (double)lnw[c + 128], lb1 = (double)lnb[c + 128];

#pragma unroll
  for (int cc = 0; cc < 2; cc++) {
    int col = c + cc * 128;
    double lw = cc ? lw1 : lw0, lb = cc ? lb1 : lb0;
#pragma unroll
    for (int pl = 0; pl < 2; pl++) {
      int pi = p0 + rh * 2 + pl;
      int b = pi / L_, l = pi % L_;
      double v = 0.0;
#pragma unroll
      for (int t = 0; t < 4; t++) {
        int i = pl * 4 + t;
        double yn = (acc[i][cc] - m_[i]) * rs_[i] * lw + lb;
        v = (v + yn) * 0.5;
        bool f = (v >= 1.0);
        out[(((size_t)t * B_ + b) * L_ + l) * H_ + col] = f ? 1.0f : 0.0f;
        if (f) v = 0.0;
      }
    }
  }
}

extern "C" void kernel_launch(void* const* d_in, const int* in_sizes, int n_in,
                              void* d_out, int out_size, void* d_ws, size_t ws_size,
                              hipStream_t stream) {
  (void)in_sizes; (void)n_in; (void)out_size; (void)ws_size;
  const float* x    = (const float*)d_in[0];
  const float* qw   = (const float*)d_in[1];
  const float* qlnw = (const float*)d_in[2];
  const float* qlnb = (const float*)d_in[3];
  const float* kw   = (const float*)d_in[4];
  const float* klnw = (const float*)d_in[5];
  const float* klnb = (const float*)d_in[6];
  const float* vw   = (const float*)d_in[7];
  const float* vlnw = (const float*)d_in[8];
  const float* vlnb = (const float*)d_in[9];
  const float* pw   = (const float*)d_in[10];
  const float* pb   = (const float*)d_in[11];
  const float* plnw = (const float*)d_in[12];
  const float* plnb = (const float*)d_in[13];

  char* ws = (char*)d_ws;
  const size_t SPK = (size_t)T_ * B_ * NH_ * L_ * DH_;     // 13,107,200 bytes
  float* wT = (float*)ws;                                  // 1 MB
  unsigned char* Qsp = (unsigned char*)(ws + (1 << 20));
  unsigned char* Ksp = Qsp + SPK;
  unsigned char* Vsp = Ksp + SPK;
  unsigned char* S2  = Vsp;                                // alias: Vsp dead after vt_prep
  unsigned char* Vt  = Vsp + SPK;                          // total ~52.5 MB

  hipLaunchKernelGGL(transpose_w, dim3(1024), dim3(256), 0, stream, qw, kw, vw, pw, wT);
  hipLaunchKernelGGL(branch_kernel, dim3(3200), dim3(256), 0, stream, x, wT,          qlnw, qlnb, Qsp);
  hipLaunchKernelGGL(branch_kernel, dim3(3200), dim3(256), 0, stream, x, wT + 65536,  klnw, klnb, Ksp);
  hipLaunchKernelGGL(branch_kernel, dim3(3200), dim3(256), 0, stream, x, wT + 131072, vlnw, vlnb, Vsp);
  hipLaunchKernelGGL(vt_prep, dim3(512), dim3(256), 0, stream, Vsp, Vt);
  hipLaunchKernelGGL(attn_mfma, dim3(896), dim3(256), 0, stream, Qsp, Ksp, Vt, S2);
  hipLaunchKernelGGL(proj_kernel, dim3(3200), dim3(256), 0, stream, S2, wT + 196608, pb, plnw, plnb, (float*)d_out);
}